// Round 10
// baseline (7014.367 us; speedup 1.0000x reference)
//
#include <hip/hip_runtime.h>
#include <cstdint>

#define CONF_THRES 0.25f
#define IOU_THRES  0.45f
#define MAX_DET    300
#define K_TOP      8192
#define NA         102000
#define NCLS       80
#define ROWLEN     85
#define CAP        32640
#define NPLANE     32
#define WIN        512
#define SSTR       9            // LDS row stride in u64 (pad 8->9: bank spread)

typedef unsigned long long u64;
typedef unsigned int u32;

// ---------------- kernel 1: wave-per-anchor scores -> sortable keys + histogram ----
__global__ __launch_bounds__(256) void score_key_kernel(const float* __restrict__ preds,
        u64* __restrict__ keys, u32* __restrict__ histP) {
#pragma clang fp contract(off)
    int lane = threadIdx.x & 63;
    int i = blockIdx.x * 4 + (threadIdx.x >> 6);     // 4 waves/block, 1 anchor/wave
    if (i >= NA) return;
    const float* p = preds + (size_t)i * ROWLEN;
    float v0 = p[lane];                               // offsets 0..63
    float v1 = (lane < ROWLEN - 64) ? p[64 + lane] : 0.0f; // offsets 64..84
    float obj = __shfl(v0, 4);
    float m = (lane >= 5) ? v0 : 0.0f;                // classes 0..58 (scores >= 0)
    m = fmaxf(m, (lane < 21) ? v1 : 0.0f);            // classes 59..79
    for (int off = 32; off; off >>= 1) m = fmaxf(m, __shfl_xor(m, off));
    if (lane == 0) {
        float score = (obj > CONF_THRES) ? m * obj : 0.0f;
        u32 sb = __float_as_uint(score);              // score >= 0: order-preserving bits
        keys[i] = ((u64)sb << 32) | (u32)(~(u32)i);   // tie-break: smaller index wins
        if (sb != 0u)
            atomicAdd(&histP[((u32)blockIdx.x & (NPLANE - 1u)) * 65536u + (sb >> 16)], 1u);
    }
}

// ---------------- kernel 1b: fold 32 histogram planes -> sumhist ----------------
__global__ __launch_bounds__(256) void reduce_hist_kernel(const u32* __restrict__ histP,
        u32* __restrict__ sumhist) {
    int bin = blockIdx.x * 256 + threadIdx.x;         // grid 256 -> 65536 bins
    u32 s = 0;
#pragma unroll
    for (int r = 0; r < NPLANE; ++r) s += histP[r * 65536 + bin];
    sumhist[bin] = s;
}

// ---------------- kernel 2: find threshold bucket for top-K (parallel scan) --------
__global__ __launch_bounds__(1024) void cutoff_kernel(const u32* __restrict__ hist,
        u32* __restrict__ meta) {
    __shared__ u32 suf[1024];
    __shared__ int cbs;
    __shared__ u32 above_s;
    int t = threadIdx.x;
    u32 s = 0;
    const u32* hb = hist + t * 64;
    for (int b = 0; b < 64; ++b) s += hb[b];
    suf[t] = s;
    if (t == 0) { cbs = -1; above_s = 0; }
    __syncthreads();
    for (int off = 1; off < 1024; off <<= 1) {
        u32 add = (t + off < 1024) ? suf[t + off] : 0u;
        __syncthreads();
        suf[t] += add;
        __syncthreads();
    }
    u32 st = suf[t];
    u32 stn = (t < 1023) ? suf[t + 1] : 0u;
    if (st >= (u32)K_TOP && stn < (u32)K_TOP) {       // at most one thread
        cbs = t;
        above_s = stn;                                 // sum of chunks above cb
    }
    __syncthreads();
    int cb = cbs;
    if (t < 64) {                                      // wave 0 does the fine pass
        u32 thresh = 0;
        if (cb >= 0) {
            u32 above = above_s;
            u32 v = hist[cb * 64 + t];
            for (int off = 1; off < 64; off <<= 1) {
                u32 o = __shfl_down(v, off);
                if (t + off < 64) v += o;
            }
            u64 bal = __ballot(v + above >= (u32)K_TOP);
            int bstar = 63 - __builtin_clzll((unsigned long long)bal);
            thresh = ((u32)(cb * 64 + bstar)) << 16;
        }
        if (t == 0) meta[1] = thresh;                  // meta[0] zeroed by memset
    }
}

// ---------------- kernel 3: compact candidates above threshold ----------------
__global__ __launch_bounds__(256) void compact_kernel(const u64* __restrict__ keys,
        u32* __restrict__ meta, u64* __restrict__ comp) {
    __shared__ u32 woff[4];
    __shared__ u32 bbase;
    int i = blockIdx.x * 256 + threadIdx.x;
    int wid = threadIdx.x >> 6, lane = threadIdx.x & 63;
    u64 key = (i < NA) ? keys[i] : 0ull;
    u32 sb = (u32)(key >> 32);
    u32 th = meta[1];
    bool take = (i < NA) && (sb != 0u) && (sb >= th);
    u64 bal = __ballot(take);
    if (lane == 0) woff[wid] = (u32)__popcll(bal);
    __syncthreads();
    if (threadIdx.x == 0) {
        u32 t0 = woff[0], t1 = woff[1], t2 = woff[2], t3 = woff[3];
        bbase = atomicAdd(&meta[0], t0 + t1 + t2 + t3);
        woff[0] = 0; woff[1] = t0; woff[2] = t0 + t1; woff[3] = t0 + t1 + t2;
    }
    __syncthreads();
    if (take) {
        u32 pos = bbase + woff[wid] + (u32)__popcll(bal & ((1ull << lane) - 1ull));
        if (pos < CAP) comp[pos] = key;
    }
}

// ---------------- kernel 4a: 2-D partial rank-by-counting ----------------
__global__ __launch_bounds__(256) void rank_partial_kernel(const u64* __restrict__ comp,
        const u32* __restrict__ meta, u32* __restrict__ rankArr) {
    __shared__ u64 tile[1024];
    u32 cnt = meta[0];
    int n = (int)(cnt < (u32)CAP ? cnt : (u32)CAP);
    int i0 = blockIdx.x * 256;
    int j0 = blockIdx.y * 1024;
    if (i0 >= n || j0 >= n) return;                  // uniform early exit
    int lim = n - j0; if (lim > 1024) lim = 1024;
    for (int k = threadIdx.x; k < 1024; k += 256)
        tile[k] = (k < lim) ? comp[j0 + k] : 0ull;
    __syncthreads();
    int i = i0 + threadIdx.x;
    if (i < n) {
        u64 key = comp[i];
        u32 r = 0;
#pragma unroll 8
        for (int j = 0; j < 1024; ++j) r += (tile[j] > key) ? 1u : 0u;
        atomicAdd(&rankArr[i], r);
    }
}

// ---------------- kernel 4b: scatter keys to their rank ----------------
__global__ __launch_bounds__(256) void scatter_kernel(const u64* __restrict__ comp,
        const u32* __restrict__ meta, const u32* __restrict__ rankArr,
        u64* __restrict__ sorted) {
    u32 cnt = meta[0];
    int n = (int)(cnt < (u32)CAP ? cnt : (u32)CAP);
    int i = blockIdx.x * 256 + threadIdx.x;
    if (i < n) {
        u32 r = rankArr[i];
        if (r < (u32)K_TOP) sorted[r] = comp[i];     // keys unique -> permutation
    }
}

// ---------------- kernel 5: wave-per-anchor gather of boxes/classes/scores ---------
__global__ __launch_bounds__(256) void gather_kernel(const u64* __restrict__ sorted,
        const float* __restrict__ preds, float* __restrict__ boxes,
        float* __restrict__ scores, float* __restrict__ classes) {
#pragma clang fp contract(off)
    int lane = threadIdx.x & 63;
    int i = blockIdx.x * 4 + (threadIdx.x >> 6);     // i in [0, 8192)
    u64 key = sorted[i];
    u32 sb = (u32)(key >> 32);
    float score = __uint_as_float(sb);
    if (score > 0.0f) {                               // uniform across the wave
        u32 idx = ~(u32)(key & 0xffffffffull);
        const float* p = preds + (size_t)idx * ROWLEN;
        float v0 = p[lane];
        float v1 = (lane < ROWLEN - 64) ? p[64 + lane] : 0.0f;
        float obj = __shfl(v0, 4);
        u64 kb = 0;
        if (lane >= 5) {
            float q = v0 * obj;                       // class lane-5
            kb = ((u64)__float_as_uint(q) << 8) | (u32)(255 - (lane - 5));
        }
        if (lane < 21) {
            float q = v1 * obj;                       // class 59+lane
            u64 kb2 = ((u64)__float_as_uint(q) << 8) | (u32)(255 - (59 + lane));
            if (kb2 > kb) kb = kb2;
        }
        for (int off = 32; off; off >>= 1) {
            u64 o = __shfl_xor(kb, off);
            if (o > kb) kb = o;
        }
        u32 cls = 255u - (u32)(kb & 0xffull);
        float x = __shfl(v0, 0), y = __shfl(v0, 1);
        float w = __shfl(v0, 2), h = __shfl(v0, 3);
        if (lane == 0) {
            boxes[i * 4 + 0] = y - h * 0.5f;          // ymin
            boxes[i * 4 + 1] = x - w * 0.5f;          // xmin
            boxes[i * 4 + 2] = y + h * 0.5f;          // ymax
            boxes[i * 4 + 3] = x + w * 0.5f;          // xmax
            scores[i] = score;
            classes[i] = (float)cls;
        }
    } else if (lane == 0) {
        boxes[i * 4 + 0] = 0.0f; boxes[i * 4 + 1] = 0.0f;
        boxes[i * 4 + 2] = 0.0f; boxes[i * 4 + 3] = 0.0f;
        scores[i] = 0.0f;
        classes[i] = 0.0f;
    }
}

// ---------------- kernel 6: 512-window suppression bitmask ----------------
// The scan only consumes rows < WIN (fallback recomputes on the fly). 512x512
// bits = 32 KB, 262k IoUs over 8 blocks -- replaces the 8192x8192 mask
// (67M IoUs + 8.4 MB writes).
__global__ __launch_bounds__(256) void mask512_kernel(const float* __restrict__ boxes,
        u64* __restrict__ win) {
#pragma clang fp contract(off)
    __shared__ float4 bx[WIN];
    int r = blockIdx.x * 64 + (threadIdx.x >> 2);     // row 0..511 (grid 8)
    int q = (threadIdx.x & 3) * 2;                    // word pair: 0,2,4,6
    for (int k = threadIdx.x; k < WIN; k += 256) bx[k] = ((const float4*)boxes)[k];
    __syncthreads();
    float4 bi = bx[r];
    float area_i = (bi.z - bi.x) * (bi.w - bi.y);
#pragma unroll
    for (int dq = 0; dq < 2; ++dq) {
        int wq = q + dq;
        int j0 = wq * 64;
        u64 bits = 0;
        if (j0 + 63 > r) {
            for (int k = 0; k < 64; ++k) {
                int j = j0 + k;
                if (j <= r) continue;
                float4 bj = bx[j];
                float area_j = (bj.z - bj.x) * (bj.w - bj.y);
                float ty = fmaxf(bi.x, bj.x);
                float tx = fmaxf(bi.y, bj.y);
                float by = fminf(bi.z, bj.z);
                float bx2 = fminf(bi.w, bj.w);
                float inter = fmaxf(by - ty, 0.0f) * fmaxf(bx2 - tx, 0.0f);
                float uni = (area_i + area_j) - inter;
                float iou = inter / (uni + 1e-9f);
                if (iou > IOU_THRES) bits |= (1ull << k);
            }
        }
        win[r * 8 + wq] = bits;
    }
}

// ---------------- kernel 6b: validity words (rem init) for the scan ----------------
__global__ __launch_bounds__(256) void valid_kernel(const float* __restrict__ scores,
        u64* __restrict__ remw) {
    int w = blockIdx.x * 4 + (threadIdx.x >> 6);      // 128 waves over 32 blocks
    int lane = threadIdx.x & 63;
    u64 b = __ballot(scores[w * 64 + lane] > 0.0f);
    if (lane == 0) remw[w] = b;
}

// ---------------- kernel 7: single-wave greedy scan, SALU-resident chain -----------
// Pop chain is scalar-only: s_ff1_b64 -> v_readlane x2 (diag slice) -> s_andn2_b64.
// No ballots in the loop (cur is wave-uniform). Cross-word suppression gathered in
// ONE butterfly per word (predicated LDS reads over all earlier keeps), 7 total
// instead of round-9's 28.
__device__ __forceinline__ u64 rfl64(u64 v) {
    u32 lo = (u32)__builtin_amdgcn_readfirstlane((int)(u32)v);
    u32 hi = (u32)__builtin_amdgcn_readfirstlane((int)(u32)(v >> 32));
    return ((u64)hi << 32) | lo;
}

__device__ __forceinline__ u64 bcast64(u64 v, int srclane) {
    u32 lo = (u32)__builtin_amdgcn_readlane((int)(u32)v, srclane);
    u32 hi = (u32)__builtin_amdgcn_readlane((int)(u32)(v >> 32), srclane);
    return ((u64)hi << 32) | lo;
}

__device__ __forceinline__ u64 shfl_xor64(u64 v, int m) {
    u32 lo = __shfl_xor((u32)v, m, 64);
    u32 hi = __shfl_xor((u32)(v >> 32), m, 64);
    return ((u64)hi << 32) | lo;
}

__device__ __forceinline__ int ffidx(u64 w0, u64 w1) {
    u64 nz0 = __ballot(w0 != 0ull);
    if (nz0 != 0ull) {
        int w = __ffsll((unsigned long long)nz0) - 1;
        u64 word = bcast64(w0, w);
        return w * 64 + __ffsll((unsigned long long)word) - 1;
    }
    u64 nz1 = __ballot(w1 != 0ull);
    if (nz1 != 0ull) {
        int w = __ffsll((unsigned long long)nz1) - 1;
        u64 word = bcast64(w1, w);
        return (w + 64) * 64 + __ffsll((unsigned long long)word) - 1;
    }
    return -1;
}

// on-the-fly suppression row for the (never-hit-on-bench) fallback path
__device__ __forceinline__ void otf_apply(const float* __restrict__ boxes, int i,
        int lane, u64& rem0, u64& rem1) {
#pragma clang fp contract(off)
    float4 bi = ((const float4*)boxes)[i];
    float ai = (bi.z - bi.x) * (bi.w - bi.y);
    u64 s0 = 0, s1 = 0;
    for (int k = 0; k < 64; ++k) {
        int j = lane * 64 + k;
        if (j > i) {
            float4 bj = ((const float4*)boxes)[j];
            float aj = (bj.z - bj.x) * (bj.w - bj.y);
            float ty = fmaxf(bi.x, bj.x), tx = fmaxf(bi.y, bj.y);
            float by = fminf(bi.z, bj.z), bx = fminf(bi.w, bj.w);
            float inter = fmaxf(by - ty, 0.0f) * fmaxf(bx - tx, 0.0f);
            float iou = inter / ((ai + aj) - inter + 1e-9f);
            if (iou > IOU_THRES) s0 |= (1ull << k);
        }
        int j2 = (64 + lane) * 64 + k;
        if (j2 > i) {
            float4 bj = ((const float4*)boxes)[j2];
            float aj = (bj.z - bj.x) * (bj.w - bj.y);
            float ty = fmaxf(bi.x, bj.x), tx = fmaxf(bi.y, bj.y);
            float by = fminf(bi.z, bj.z), bx = fminf(bi.w, bj.w);
            float inter = fmaxf(by - ty, 0.0f) * fmaxf(bx - tx, 0.0f);
            float iou = inter / ((ai + aj) - inter + 1e-9f);
            if (iou > IOU_THRES) s1 |= (1ull << k);
        }
    }
    rem0 &= ~s0; rem1 &= ~s1;
}

__global__ __launch_bounds__(64) void nms_scan_kernel(const u64* __restrict__ win,
        const u64* __restrict__ remw, const float* __restrict__ boxes,
        const float* __restrict__ scores, const float* __restrict__ classes,
        float* __restrict__ out) {
#pragma clang fp contract(off)
    __shared__ u64 sub[WIN * SSTR];                   // 36 KB padded window submatrix
    __shared__ u32 ki[MAX_DET + 4];                   // kept indices
    int lane = threadIdx.x;                           // exactly one wave
    // stage contiguous 32 KB window into padded LDS (independent loads)
#pragma unroll 8
    for (int it = 0; it < 32; ++it) {
        int idx = it * 64 + lane;                     // uint4 index over win[4096 u64]
        uint4 v = ((const uint4*)win)[idx];
        int t = idx >> 2;
        int w = (idx & 3) * 2;
        sub[t * SSTR + w]     = ((u64)v.y << 32) | v.x;
        sub[t * SSTR + w + 1] = ((u64)v.w << 32) | v.z;
    }
    __syncthreads();
    u64 diag[8];
#pragma unroll
    for (int w = 0; w < 8; ++w) diag[w] = sub[(w * 64 + lane) * SSTR + w];
    u64 remv[8];
#pragma unroll
    for (int w = 0; w < 8; ++w) remv[w] = remw[w];    // broadcast loads
    u64 keptW[8] = {0, 0, 0, 0, 0, 0, 0, 0};
    int n = 0;
#pragma unroll
    for (int w = 0; w < 8; ++w) {
        if (n < MAX_DET) {
            // batched cross-word suppression from all keeps in words < w
            u64 acc = 0;
#pragma unroll
            for (int wp = 0; wp < 8; ++wp) {
                if (wp < w) {
                    if ((keptW[wp] >> lane) & 1ull)
                        acc |= sub[(wp * 64 + lane) * SSTR + w];
                }
            }
            for (int off = 32; off; off >>= 1) acc |= shfl_xor64(acc, off);
            u64 cur = rfl64(remv[w]) & ~rfl64(acc);
            u64 kw = 0;
            while (cur != 0ull && n < MAX_DET) {      // uniform scalar loop
                int b = __ffsll((unsigned long long)cur) - 1;
                u64 slice = bcast64(diag[w], b);      // row (w*64+b), word w
                kw |= (1ull << b);
                cur &= ~(slice | (1ull << b));
                ++n;
            }
            keptW[w] = kw;
        }
    }
    // reconstruct kept-index list in LDS (parallel; ascending order = greedy order)
    int base = 0;
#pragma unroll
    for (int w = 0; w < 8; ++w) {
        u64 kw = keptW[w];
        if ((kw >> lane) & 1ull) {
            int r = (int)__popcll(kw & ((1ull << lane) - 1ull));
            ki[base + r] = (u32)(w * 64 + lane);
        }
        base += (int)__popcll(kw);
    }
    __syncthreads();
    // ---- fallback: window exhausted with n < MAX_DET (not hit for bench input) ----
    if (n < MAX_DET) {
        u64 rem0 = (lane < 8) ? 0ull : remw[lane];    // window fully consumed
        u64 rem1 = remw[64 + lane];
        if ((__ballot(rem0 != 0ull) | __ballot(rem1 != 0ull)) != 0ull) {
            for (int m = 0; m < n; ++m)               // apply window keeps (on-the-fly)
                otf_apply(boxes, (int)ki[m], lane, rem0, rem1);
            while (n < MAX_DET) {
                int i = ffidx(rem0, rem1);
                if (i < 0) break;
                if (lane == 0) ki[n] = (u32)i;
                ++n;
                otf_apply(boxes, i, lane, rem0, rem1);
                int wi = i >> 6;
                if (wi < 64) { if (lane == wi) rem0 &= ~(1ull << (i & 63)); }
                else         { if (lane == wi - 64) rem1 &= ~(1ull << (i & 63)); }
            }
            __syncthreads();
        }
    }
    // ---- parallel output phase: lane m handles detection m (5 strided rounds) ----
    for (int m = lane; m < MAX_DET; m += 64) {
        float4 b = make_float4(0.0f, 0.0f, 0.0f, 0.0f);
        float c = 0.0f, s = 0.0f;
        if (m < n) {
            int k = (int)ki[m];
            b = ((const float4*)boxes)[k];
            c = classes[k];
            s = scores[k];
        }
        ((float4*)out)[m] = b;
        out[1200 + m] = c;
        out[1500 + m] = s;
    }
}

// ---------------- launch ----------------
extern "C" void kernel_launch(void* const* d_in, const int* in_sizes, int n_in,
                              void* d_out, int out_size, void* d_ws, size_t ws_size,
                              hipStream_t stream) {
    const float* preds = (const float*)d_in[0];
    char* ws = (char*)d_ws;

    // ws layout (bytes), total 9991104:
    //   [0, 262144)            sumhist     u32[65536]
    //   [262144, 262208)       meta        u32[16]   ([0]=counter, [1]=thresh)
    //   [262208, 263232)       remw        u64[128]
    //   [263232, 328768)       sorted      u64[8192]
    //   [328768, 1144768)      keys        u64[102000] (dead after compact;
    //                                      front 130560 B reused as rankArr)
    //   [1144768, 1405888)     comp        u64[32640]
    //   [1405888, 1536960)     top_boxes   f32[8192*4]
    //   [1536960, 1569728)     top_scores  f32[8192]
    //   [1569728, 1602496)     top_classes f32[8192]
    //   [1602496, ...)         win         u64[512*8] (32 KB; region also hosts the
    //                                      32-plane histogram earlier in the graph)
    u32*   sumhist = (u32*)(ws + 0);
    u32*   meta    = (u32*)(ws + 262144);
    u64*   remw    = (u64*)(ws + 262208);
    u64*   sorted  = (u64*)(ws + 263232);
    u64*   keys    = (u64*)(ws + 328768);
    u32*   rankArr = (u32*)(ws + 328768);            // aliases keys (dead by then)
    u64*   comp    = (u64*)(ws + 1144768);
    float* tboxes  = (float*)(ws + 1405888);
    float* tscores = (float*)(ws + 1536960);
    float* tclass  = (float*)(ws + 1569728);
    u64*   win     = (u64*)(ws + 1602496);
    u32*   histP   = (u32*)(ws + 1602496);           // aliases win region (earlier)
    float* out     = (float*)d_out;

    hipMemsetAsync(ws, 0, 328768, stream);           // sumhist+meta+remw+sorted
    hipMemsetAsync(histP, 0, (size_t)NPLANE * 65536 * 4, stream);  // hist planes (8 MB)

    score_key_kernel<<<(NA + 3) / 4, 256, 0, stream>>>(preds, keys, histP);
    reduce_hist_kernel<<<256, 256, 0, stream>>>(histP, sumhist);
    cutoff_kernel<<<1, 1024, 0, stream>>>(sumhist, meta);
    compact_kernel<<<(NA + 255) / 256, 256, 0, stream>>>(keys, meta, comp);
    hipMemsetAsync(rankArr, 0, (size_t)CAP * 4, stream);   // keys dead: zero rankArr
    rank_partial_kernel<<<dim3((CAP + 255) / 256, (CAP + 1023) / 1024), 256, 0, stream>>>(
            comp, meta, rankArr);
    scatter_kernel<<<(CAP + 255) / 256, 256, 0, stream>>>(comp, meta, rankArr, sorted);
    gather_kernel<<<K_TOP / 4, 256, 0, stream>>>(sorted, preds, tboxes, tscores, tclass);
    mask512_kernel<<<8, 256, 0, stream>>>(tboxes, win);
    valid_kernel<<<32, 256, 0, stream>>>(tscores, remw);
    nms_scan_kernel<<<1, 64, 0, stream>>>(win, remw, tboxes, tscores, tclass, out);
}

// Round 11
// 212.962 us; speedup vs baseline: 32.9372x; 32.9372x over previous
//
#include <hip/hip_runtime.h>
#include <cstdint>

#define CONF_THRES 0.25f
#define IOU_THRES  0.45f
#define MAX_DET    300
#define K_TOP      8192
#define NA         102000
#define NCLS       80
#define ROWLEN     85
#define CAP        32640
#define NPLANE     32
#define WIN        512
#define NWIN       (K_TOP / WIN)
#define SSTR       9            // LDS row stride in u64 (pad 8->9: bank spread)

typedef unsigned long long u64;
typedef unsigned int u32;

// ---------------- kernel 1: wave-per-anchor scores -> sortable keys + histogram ----
__global__ __launch_bounds__(256) void score_key_kernel(const float* __restrict__ preds,
        u64* __restrict__ keys, u32* __restrict__ histP) {
#pragma clang fp contract(off)
    int lane = threadIdx.x & 63;
    int i = blockIdx.x * 4 + (threadIdx.x >> 6);     // 4 waves/block, 1 anchor/wave
    if (i >= NA) return;
    const float* p = preds + (size_t)i * ROWLEN;
    float v0 = p[lane];                               // offsets 0..63
    float v1 = (lane < ROWLEN - 64) ? p[64 + lane] : 0.0f; // offsets 64..84
    float obj = __shfl(v0, 4);
    float m = (lane >= 5) ? v0 : 0.0f;                // classes 0..58 (scores >= 0)
    m = fmaxf(m, (lane < 21) ? v1 : 0.0f);            // classes 59..79
    for (int off = 32; off; off >>= 1) m = fmaxf(m, __shfl_xor(m, off));
    if (lane == 0) {
        float score = (obj > CONF_THRES) ? m * obj : 0.0f;
        u32 sb = __float_as_uint(score);              // score >= 0: order-preserving bits
        keys[i] = ((u64)sb << 32) | (u32)(~(u32)i);   // tie-break: smaller index wins
        if (sb != 0u)
            atomicAdd(&histP[((u32)blockIdx.x & (NPLANE - 1u)) * 65536u + (sb >> 16)], 1u);
    }
}

// ---------------- kernel 1b: fold 32 histogram planes -> sumhist ----------------
__global__ __launch_bounds__(256) void reduce_hist_kernel(const u32* __restrict__ histP,
        u32* __restrict__ sumhist) {
    int bin = blockIdx.x * 256 + threadIdx.x;         // grid 256 -> 65536 bins
    u32 s = 0;
#pragma unroll
    for (int r = 0; r < NPLANE; ++r) s += histP[r * 65536 + bin];
    sumhist[bin] = s;
}

// ---------------- kernel 2: find threshold bucket for top-K (parallel scan) --------
__global__ __launch_bounds__(1024) void cutoff_kernel(const u32* __restrict__ hist,
        u32* __restrict__ meta) {
    __shared__ u32 suf[1024];
    __shared__ int cbs;
    __shared__ u32 above_s;
    int t = threadIdx.x;
    u32 s = 0;
    const u32* hb = hist + t * 64;
    for (int b = 0; b < 64; ++b) s += hb[b];
    suf[t] = s;
    if (t == 0) { cbs = -1; above_s = 0; }
    __syncthreads();
    for (int off = 1; off < 1024; off <<= 1) {
        u32 add = (t + off < 1024) ? suf[t + off] : 0u;
        __syncthreads();
        suf[t] += add;
        __syncthreads();
    }
    u32 st = suf[t];
    u32 stn = (t < 1023) ? suf[t + 1] : 0u;
    if (st >= (u32)K_TOP && stn < (u32)K_TOP) {       // at most one thread
        cbs = t;
        above_s = stn;                                 // sum of chunks above cb
    }
    __syncthreads();
    int cb = cbs;
    if (t < 64) {                                      // wave 0 does the fine pass
        u32 thresh = 0;
        if (cb >= 0) {
            u32 above = above_s;
            u32 v = hist[cb * 64 + t];
            for (int off = 1; off < 64; off <<= 1) {
                u32 o = __shfl_down(v, off);
                if (t + off < 64) v += o;
            }
            u64 bal = __ballot(v + above >= (u32)K_TOP);
            int bstar = 63 - __builtin_clzll((unsigned long long)bal);
            thresh = ((u32)(cb * 64 + bstar)) << 16;
        }
        if (t == 0) meta[1] = thresh;                  // meta[0] zeroed by memset
    }
}

// ---------------- kernel 3: compact candidates above threshold ----------------
__global__ __launch_bounds__(256) void compact_kernel(const u64* __restrict__ keys,
        u32* __restrict__ meta, u64* __restrict__ comp) {
    __shared__ u32 woff[4];
    __shared__ u32 bbase;
    int i = blockIdx.x * 256 + threadIdx.x;
    int wid = threadIdx.x >> 6, lane = threadIdx.x & 63;
    u64 key = (i < NA) ? keys[i] : 0ull;
    u32 sb = (u32)(key >> 32);
    u32 th = meta[1];
    bool take = (i < NA) && (sb != 0u) && (sb >= th);
    u64 bal = __ballot(take);
    if (lane == 0) woff[wid] = (u32)__popcll(bal);
    __syncthreads();
    if (threadIdx.x == 0) {
        u32 t0 = woff[0], t1 = woff[1], t2 = woff[2], t3 = woff[3];
        bbase = atomicAdd(&meta[0], t0 + t1 + t2 + t3);
        woff[0] = 0; woff[1] = t0; woff[2] = t0 + t1; woff[3] = t0 + t1 + t2;
    }
    __syncthreads();
    if (take) {
        u32 pos = bbase + woff[wid] + (u32)__popcll(bal & ((1ull << lane) - 1ull));
        if (pos < CAP) comp[pos] = key;
    }
}

// ---------------- kernel 4a: 2-D partial rank-by-counting ----------------
__global__ __launch_bounds__(256) void rank_partial_kernel(const u64* __restrict__ comp,
        const u32* __restrict__ meta, u32* __restrict__ rankArr) {
    __shared__ u64 tile[1024];
    u32 cnt = meta[0];
    int n = (int)(cnt < (u32)CAP ? cnt : (u32)CAP);
    int i0 = blockIdx.x * 256;
    int j0 = blockIdx.y * 1024;
    if (i0 >= n || j0 >= n) return;                  // uniform early exit
    int lim = n - j0; if (lim > 1024) lim = 1024;
    for (int k = threadIdx.x; k < 1024; k += 256)
        tile[k] = (k < lim) ? comp[j0 + k] : 0ull;
    __syncthreads();
    int i = i0 + threadIdx.x;
    if (i < n) {
        u64 key = comp[i];
        u32 r = 0;
#pragma unroll 8
        for (int j = 0; j < 1024; ++j) r += (tile[j] > key) ? 1u : 0u;
        atomicAdd(&rankArr[i], r);
    }
}

// ---------------- kernel 4b: scatter keys to their rank ----------------
__global__ __launch_bounds__(256) void scatter_kernel(const u64* __restrict__ comp,
        const u32* __restrict__ meta, const u32* __restrict__ rankArr,
        u64* __restrict__ sorted) {
    u32 cnt = meta[0];
    int n = (int)(cnt < (u32)CAP ? cnt : (u32)CAP);
    int i = blockIdx.x * 256 + threadIdx.x;
    if (i < n) {
        u32 r = rankArr[i];
        if (r < (u32)K_TOP) sorted[r] = comp[i];     // keys unique -> permutation
    }
}

// ---------------- kernel 5: wave-per-anchor gather of boxes/classes/scores ---------
__global__ __launch_bounds__(256) void gather_kernel(const u64* __restrict__ sorted,
        const float* __restrict__ preds, float* __restrict__ boxes,
        float* __restrict__ scores, float* __restrict__ classes) {
#pragma clang fp contract(off)
    int lane = threadIdx.x & 63;
    int i = blockIdx.x * 4 + (threadIdx.x >> 6);     // i in [0, 8192)
    u64 key = sorted[i];
    u32 sb = (u32)(key >> 32);
    float score = __uint_as_float(sb);
    if (score > 0.0f) {                               // uniform across the wave
        u32 idx = ~(u32)(key & 0xffffffffull);
        const float* p = preds + (size_t)idx * ROWLEN;
        float v0 = p[lane];
        float v1 = (lane < ROWLEN - 64) ? p[64 + lane] : 0.0f;
        float obj = __shfl(v0, 4);
        u64 kb = 0;
        if (lane >= 5) {
            float q = v0 * obj;                       // class lane-5
            kb = ((u64)__float_as_uint(q) << 8) | (u32)(255 - (lane - 5));
        }
        if (lane < 21) {
            float q = v1 * obj;                       // class 59+lane
            u64 kb2 = ((u64)__float_as_uint(q) << 8) | (u32)(255 - (59 + lane));
            if (kb2 > kb) kb = kb2;
        }
        for (int off = 32; off; off >>= 1) {
            u64 o = __shfl_xor(kb, off);
            if (o > kb) kb = o;
        }
        u32 cls = 255u - (u32)(kb & 0xffull);
        float x = __shfl(v0, 0), y = __shfl(v0, 1);
        float w = __shfl(v0, 2), h = __shfl(v0, 3);
        if (lane == 0) {
            boxes[i * 4 + 0] = y - h * 0.5f;          // ymin
            boxes[i * 4 + 1] = x - w * 0.5f;          // xmin
            boxes[i * 4 + 2] = y + h * 0.5f;          // ymax
            boxes[i * 4 + 3] = x + w * 0.5f;          // xmax
            scores[i] = score;
            classes[i] = (float)cls;
        }
    } else if (lane == 0) {
        boxes[i * 4 + 0] = 0.0f; boxes[i * 4 + 1] = 0.0f;
        boxes[i * 4 + 2] = 0.0f; boxes[i * 4 + 3] = 0.0f;
        scores[i] = 0.0f;
        classes[i] = 0.0f;
    }
}

// ---------------- kernel 6: full suppression bitmask (iou > thres, j > i) ----------
// Restored: the scan's reach extends past any fixed small window (round-10 post-
// mortem: FETCH in rounds 7-9 showed ~190 fallback row reads). ~33M upper-triangle
// IoUs fully parallel (~10us) + 8.4MB writes.
__global__ __launch_bounds__(256) void mask_kernel(const float* __restrict__ boxes,
        u64* __restrict__ mask) {
#pragma clang fp contract(off)
    __shared__ float4 cb[64];
    int wj = blockIdx.x;                 // column word 0..127
    int i = blockIdx.y * 256 + threadIdx.x;
    int j0 = wj * 64;
    if (threadIdx.x < 64) cb[threadIdx.x] = ((const float4*)boxes)[j0 + threadIdx.x];
    __syncthreads();
    float4 bi = ((const float4*)boxes)[i];
    float area_i = (bi.z - bi.x) * (bi.w - bi.y);
    u64 bits = 0;
    if (j0 + 63 > i) {
        for (int k = 0; k < 64; ++k) {
            int j = j0 + k;
            if (j <= i) continue;
            float4 bj = cb[k];
            float area_j = (bj.z - bj.x) * (bj.w - bj.y);
            float ty = fmaxf(bi.x, bj.x);
            float tx = fmaxf(bi.y, bj.y);
            float by = fminf(bi.z, bj.z);
            float bx = fminf(bi.w, bj.w);
            float inter = fmaxf(by - ty, 0.0f) * fmaxf(bx - tx, 0.0f);
            float uni = (area_i + area_j) - inter;
            float iou = inter / (uni + 1e-9f);
            if (iou > IOU_THRES) bits |= (1ull << k);
        }
    }
    mask[(size_t)i * 128 + wj] = bits;
}

// ---------------- kernel 6b: validity words (rem init) for the scan ----------------
__global__ __launch_bounds__(256) void valid_kernel(const float* __restrict__ scores,
        u64* __restrict__ remw) {
    int w = blockIdx.x * 4 + (threadIdx.x >> 6);      // 128 waves over 32 blocks
    int lane = threadIdx.x & 63;
    u64 b = __ballot(scores[w * 64 + lane] > 0.0f);
    if (lane == 0) remw[w] = b;
}

// ---------------- kernel 7: single-wave greedy scan, 16 LDS windows, no fallback ---
// Per 512-window: stage the diagonal 512x512 block (32 KB, coalesced), fold the
// suppression of ALL earlier keeps in parallel (lane m reads keep m's 64B row
// segment for this window; one OR-butterfly), then run the register/SALU pop chain
// (~40cy/keep). Windows cover all 8192 candidates -> scan is complete by
// construction; loop breaks as soon as n == MAX_DET.
__device__ __forceinline__ u64 rfl64(u64 v) {
    u32 lo = (u32)__builtin_amdgcn_readfirstlane((int)(u32)v);
    u32 hi = (u32)__builtin_amdgcn_readfirstlane((int)(u32)(v >> 32));
    return ((u64)hi << 32) | lo;
}

__device__ __forceinline__ u64 bcast64(u64 v, int srclane) {
    u32 lo = (u32)__builtin_amdgcn_readlane((int)(u32)v, srclane);
    u32 hi = (u32)__builtin_amdgcn_readlane((int)(u32)(v >> 32), srclane);
    return ((u64)hi << 32) | lo;
}

__device__ __forceinline__ u64 shfl_xor64(u64 v, int m) {
    u32 lo = __shfl_xor((u32)v, m, 64);
    u32 hi = __shfl_xor((u32)(v >> 32), m, 64);
    return ((u64)hi << 32) | lo;
}

__global__ __launch_bounds__(64) void nms_scan_kernel(const u64* __restrict__ mask,
        const u64* __restrict__ remw, const float* __restrict__ boxes,
        const float* __restrict__ scores, const float* __restrict__ classes,
        float* __restrict__ out) {
    __shared__ u64 sub[WIN * SSTR];                   // 36 KB padded window submatrix
    __shared__ u32 ki[MAX_DET + 8];                   // kept indices (ascending)
    int lane = threadIdx.x;                           // exactly one wave
    int n = 0;
    for (int win = 0; win < NWIN && n < MAX_DET; ++win) {
        int rbase = win * WIN;
        __syncthreads();                              // prev window's sub reads done
        // stage diag window: rows [rbase, rbase+WIN) x words [win*8, win*8+8)
#pragma unroll 8
        for (int it = 0; it < 32; ++it) {
            int idx = it * 64 + lane;                 // uint4 index, 2048 total
            int r = idx >> 2, j = (idx & 3) * 2;
            uint4 v = *(const uint4*)&mask[(size_t)(rbase + r) * 128 + win * 8 + j];
            sub[r * SSTR + j]     = ((u64)v.y << 32) | v.x;
            sub[r * SSTR + j + 1] = ((u64)v.w << 32) | v.z;
        }
        // fold suppression from keeps in earlier windows (parallel over keeps)
        u64 acc[8] = {0, 0, 0, 0, 0, 0, 0, 0};
        for (int m = lane; m < n; m += 64) {
            int k = (int)ki[m];
            const u64* rp = &mask[(size_t)k * 128 + win * 8];
#pragma unroll
            for (int j = 0; j < 8; ++j) acc[j] |= rp[j];
        }
#pragma unroll
        for (int j = 0; j < 8; ++j)
            for (int off = 32; off; off >>= 1) acc[j] |= shfl_xor64(acc[j], off);
        __syncthreads();
        u64 diag[8];
#pragma unroll
        for (int sw = 0; sw < 8; ++sw) diag[sw] = sub[(sw * 64 + lane) * SSTR + sw];
        int n0 = n;
        u64 keptW[8] = {0, 0, 0, 0, 0, 0, 0, 0};
#pragma unroll
        for (int sw = 0; sw < 8; ++sw) {
            if (n < MAX_DET) {
                // suppression from keeps in earlier subwords of THIS window
                u64 acc2 = 0;
#pragma unroll
                for (int wp = 0; wp < 8; ++wp) {
                    if (wp < sw) {
                        if ((keptW[wp] >> lane) & 1ull)
                            acc2 |= sub[(wp * 64 + lane) * SSTR + sw];
                    }
                }
                for (int off = 32; off; off >>= 1) acc2 |= shfl_xor64(acc2, off);
                u64 cur = rfl64(remw[win * 8 + sw]) & ~rfl64(acc[sw]) & ~rfl64(acc2);
                u64 kw = 0;
                while (cur != 0ull && n < MAX_DET) {  // uniform scalar pop chain
                    int b = __ffsll((unsigned long long)cur) - 1;
                    u64 slice = bcast64(diag[sw], b); // row (sw*64+b), word sw
                    kw |= (1ull << b);
                    cur &= ~(slice | (1ull << b));
                    ++n;
                }
                keptW[sw] = kw;
            }
        }
        // append kept indices (parallel; ascending index = greedy order)
        int base = n0;
#pragma unroll
        for (int sw = 0; sw < 8; ++sw) {
            u64 kw = keptW[sw];
            if ((kw >> lane) & 1ull) {
                int rr = (int)__popcll(kw & ((1ull << lane) - 1ull));
                ki[base + rr] = (u32)(rbase + sw * 64 + lane);
            }
            base += (int)__popcll(kw);
        }
        __syncthreads();
    }
    __syncthreads();
    // ---- parallel output phase: lane m handles detection m (5 strided rounds) ----
    for (int m = lane; m < MAX_DET; m += 64) {
        float4 b = make_float4(0.0f, 0.0f, 0.0f, 0.0f);
        float c = 0.0f, s = 0.0f;
        if (m < n) {
            int k = (int)ki[m];
            b = ((const float4*)boxes)[k];
            c = classes[k];
            s = scores[k];
        }
        ((float4*)out)[m] = b;
        out[1200 + m] = c;
        out[1500 + m] = s;
    }
}

// ---------------- launch ----------------
extern "C" void kernel_launch(void* const* d_in, const int* in_sizes, int n_in,
                              void* d_out, int out_size, void* d_ws, size_t ws_size,
                              hipStream_t stream) {
    const float* preds = (const float*)d_in[0];
    char* ws = (char*)d_ws;

    // ws layout (bytes), total 9991104:
    //   [0, 262144)            sumhist     u32[65536]
    //   [262144, 262208)       meta        u32[16]   ([0]=counter, [1]=thresh)
    //   [262208, 263232)       remw        u64[128]
    //   [263232, 328768)       sorted      u64[8192]
    //   [328768, 1144768)      keys        u64[102000] (dead after compact;
    //                                      front 130560 B reused as rankArr)
    //   [1144768, 1405888)     comp        u64[32640]
    //   [1405888, 1536960)     top_boxes   f32[8192*4]
    //   [1536960, 1569728)     top_scores  f32[8192]
    //   [1569728, 1602496)     top_classes f32[8192]
    //   [1602496, 9991104)     mask        u64[8192*128]  (8 MB; doubles as the
    //                                      32-plane histogram before mask_kernel)
    u32*   sumhist = (u32*)(ws + 0);
    u32*   meta    = (u32*)(ws + 262144);
    u64*   remw    = (u64*)(ws + 262208);
    u64*   sorted  = (u64*)(ws + 263232);
    u64*   keys    = (u64*)(ws + 328768);
    u32*   rankArr = (u32*)(ws + 328768);            // aliases keys (dead by then)
    u64*   comp    = (u64*)(ws + 1144768);
    float* tboxes  = (float*)(ws + 1405888);
    float* tscores = (float*)(ws + 1536960);
    float* tclass  = (float*)(ws + 1569728);
    u64*   mask    = (u64*)(ws + 1602496);
    u32*   histP   = (u32*)(ws + 1602496);           // aliases mask region (earlier)
    float* out     = (float*)d_out;

    hipMemsetAsync(ws, 0, 328768, stream);           // sumhist+meta+remw+sorted
    hipMemsetAsync(histP, 0, (size_t)NPLANE * 65536 * 4, stream);  // hist planes (8 MB)

    score_key_kernel<<<(NA + 3) / 4, 256, 0, stream>>>(preds, keys, histP);
    reduce_hist_kernel<<<256, 256, 0, stream>>>(histP, sumhist);
    cutoff_kernel<<<1, 1024, 0, stream>>>(sumhist, meta);
    compact_kernel<<<(NA + 255) / 256, 256, 0, stream>>>(keys, meta, comp);
    hipMemsetAsync(rankArr, 0, (size_t)CAP * 4, stream);   // keys dead: zero rankArr
    rank_partial_kernel<<<dim3((CAP + 255) / 256, (CAP + 1023) / 1024), 256, 0, stream>>>(
            comp, meta, rankArr);
    scatter_kernel<<<(CAP + 255) / 256, 256, 0, stream>>>(comp, meta, rankArr, sorted);
    gather_kernel<<<K_TOP / 4, 256, 0, stream>>>(sorted, preds, tboxes, tscores, tclass);
    mask_kernel<<<dim3(128, K_TOP / 256), 256, 0, stream>>>(tboxes, mask);
    valid_kernel<<<32, 256, 0, stream>>>(tscores, remw);
    nms_scan_kernel<<<1, 64, 0, stream>>>(mask, remw, tboxes, tscores, tclass, out);
}